// Round 2
// baseline (611.497 us; speedup 1.0000x reference)
//
#include <hip/hip_runtime.h>
#include <hip/hip_cooperative_groups.h>

namespace cg = cooperative_groups;

#define B 8
#define S 1024
#define DM 512
#define H 8
#define D 64

typedef __attribute__((ext_vector_type(8))) short bf16x8;
typedef __attribute__((ext_vector_type(4))) float f32x4;

__device__ inline f32x4 mfma16(bf16x8 a, bf16x8 b, f32x4 c) {
  return __builtin_amdgcn_mfma_f32_16x16x32_bf16(a, b, c, 0, 0, 0);
}

__device__ inline ushort f2bf(float f) {
  uint u = __float_as_uint(f);
  u += 0x7fff + ((u >> 16) & 1);   // round-to-nearest-even
  return (ushort)(u >> 16);
}

// LDS is shared across phases; phases are separated by grid.sync().
union SMem {
  struct { ushort As[64][72]; ushort Bs[64][72]; } g;   // 18.4 KB (GEMM phases)
  struct { ushort Pl[16 * 1024];                         // 32 KB swizzled P
           float redm[4][16]; float redsum[4][16]; } a;  // attn phase
};

// ---------------------------------------------------------------------------
// One cooperative kernel, 4 phases:
//   P0 prep (cast x -> bf16, transpose-pack W into WT / WoT)
//   P1 qkv GEMM  (64x64 tiles, reg-staged LDS, proven 190.4us structure)
//   P2 attention (scores-in-regs, swizzled-LDS P, proven structure)
//   P3 out-proj GEMM (64x64 tiles)
// Grid-stride everywhere so any co-resident grid size is correct.
// ---------------------------------------------------------------------------
__global__ __launch_bounds__(256, 4) void mega_kernel(
    const float* __restrict__ x, const float* __restrict__ Wq,
    const float* __restrict__ Wk, const float* __restrict__ Wv,
    const float* __restrict__ Wo, float* __restrict__ z,
    float* __restrict__ attnO, ushort* __restrict__ xbf,
    ushort* __restrict__ WT, ushort* __restrict__ WoT,
    ushort* __restrict__ qb, ushort* __restrict__ kb,
    ushort* __restrict__ vt, ushort* __restrict__ concat) {
  __shared__ SMem sm;
  cg::grid_group grid = cg::this_grid();
  const int tid = threadIdx.x;
  const int nthr = gridDim.x * 256;

  // ---- P0: prep ---------------------------------------------------------
  {
    const int NX = 1 << 20;            // x cast, one float4 per item
    const int NWT = 3 * 8 * 512 * 64;  // 786432, coalesced W reads
    const int tot = NX + NWT + 512 * 512;
    for (int idx = blockIdx.x * 256 + tid; idx < tot; idx += nthr) {
      if (idx < NX) {
        float4 v = *(const float4*)(x + (size_t)idx * 4);
        ushort4 o;
        o.x = f2bf(v.x); o.y = f2bf(v.y); o.z = f2bf(v.z); o.w = f2bf(v.w);
        *(ushort4*)(xbf + (size_t)idx * 4) = o;
      } else if (idx < NX + NWT) {
        int i2 = idx - NX;
        int g = i2 >> 18, rem = i2 & 262143;   // h*32768 + m*64 + d
        const float* W = (g == 0) ? Wq : (g == 1) ? Wk : Wv;
        float val = W[rem];                    // coalesced read
        int d = rem & 63, m = (rem >> 6) & 511, h = rem >> 15;
        WT[((size_t)(g << 9) + (h << 6) + d) * 512 + m] = f2bf(val);
      } else {
        int i2 = idx - NX - NWT;
        int m = i2 & 511, f = i2 >> 9;
        WoT[(size_t)m * 512 + f] = f2bf(Wo[(size_t)f * DM + m]);
      }
    }
  }
  grid.sync();

  // ---- P1: QKV GEMM  C[s][f] = sum_m xbf[s][m]*WT[f][m]  (8192x1536x512) --
  {
    const int w = tid >> 6, l = tid & 63;
    const int r = l & 15, qq = l >> 4;
    const int mh = (w >> 1) * 32, nh = (w & 1) * 32;
    const int srow = tid >> 2, sco = (tid & 3) * 16;
    for (int t = blockIdx.x; t < 3072; t += gridDim.x) {   // 128 x 24 tiles
      const int m0 = (t & 127) * 64, n0 = (t >> 7) * 64;
      f32x4 acc[2][2] = {};
      for (int k0 = 0; k0 < 512; k0 += 64) {
        const ushort* ap = xbf + (size_t)(m0 + srow) * 512 + k0 + sco;
        const ushort* bp = WT + (size_t)(n0 + srow) * 512 + k0 + sco;
        uint4 a0 = *(const uint4*)ap;
        uint4 a1 = *(const uint4*)(ap + 8);
        uint4 b0 = *(const uint4*)bp;
        uint4 b1 = *(const uint4*)(bp + 8);
        __syncthreads();
        *(uint4*)&sm.g.As[srow][sco] = a0;
        *(uint4*)&sm.g.As[srow][sco + 8] = a1;
        *(uint4*)&sm.g.Bs[srow][sco] = b0;
        *(uint4*)&sm.g.Bs[srow][sco + 8] = b1;
        __syncthreads();
        #pragma unroll
        for (int kk = 0; kk < 64; kk += 32) {
          bf16x8 fa0 = *(const bf16x8*)&sm.g.As[mh + r][kk + qq * 8];
          bf16x8 fa1 = *(const bf16x8*)&sm.g.As[mh + 16 + r][kk + qq * 8];
          bf16x8 fb0 = *(const bf16x8*)&sm.g.Bs[nh + r][kk + qq * 8];
          bf16x8 fb1 = *(const bf16x8*)&sm.g.Bs[nh + 16 + r][kk + qq * 8];
          acc[0][0] = mfma16(fa0, fb0, acc[0][0]);
          acc[0][1] = mfma16(fa0, fb1, acc[0][1]);
          acc[1][0] = mfma16(fa1, fb0, acc[1][0]);
          acc[1][1] = mfma16(fa1, fb1, acc[1][1]);
        }
      }
      const int g = n0 >> 9;                   // 0=q 1=k 2=v, block-uniform
      #pragma unroll
      for (int mi = 0; mi < 2; ++mi)
        #pragma unroll
        for (int nj = 0; nj < 2; ++nj)
          #pragma unroll
          for (int i = 0; i < 4; ++i) {
            int row = m0 + mh + mi * 16 + qq * 4 + i;
            int col = n0 + nh + nj * 16 + r;
            int bb = row >> 10, s = row & 1023;
            int fl = col & 511, h = fl >> 6, d = fl & 63;
            ushort val = f2bf(acc[mi][nj][i]);
            if (g == 0)
              qb[(((size_t)bb * H + h) * S + s) * D + d] = val;
            else if (g == 1)
              kb[(((size_t)bb * H + h) * S + s) * D + d] = val;
            else
              vt[(((size_t)bb * H + h) * D + d) * S + s] = val;
          }
    }
  }
  grid.sync();

  // ---- P2: attention ----------------------------------------------------
  {
    const int w = tid >> 6, l = tid & 63;
    const int r = l & 15, qq = l >> 4;
    for (int t = blockIdx.x; t < 4096; t += gridDim.x) {
      __syncthreads();                         // guard Pl reuse across iters
      const int s0 = (t & 63) * 16, bh = t >> 6;

      const ushort* qp = qb + ((size_t)bh * S + s0) * D;
      bf16x8 qa0 = *(const bf16x8*)(qp + r * 64 + qq * 8);
      bf16x8 qa1 = *(const bf16x8*)(qp + r * 64 + 32 + qq * 8);

      const ushort* kp = kb + (size_t)bh * S * D;
      f32x4 sc[16];
      #pragma unroll
      for (int kt = 0; kt < 16; ++kt) {
        const ushort* kr = kp + (size_t)(w * 256 + kt * 16 + r) * 64 + qq * 8;
        bf16x8 kf0 = *(const bf16x8*)kr;
        bf16x8 kf1 = *(const bf16x8*)(kr + 32);
        f32x4 a = {};
        a = mfma16(qa0, kf0, a);
        a = mfma16(qa1, kf1, a);
        sc[kt] = a * 0.125f;
      }

      float mx[4];
      #pragma unroll
      for (int i = 0; i < 4; ++i) {
        float m = sc[0][i];
        #pragma unroll
        for (int kt = 1; kt < 16; ++kt) m = fmaxf(m, sc[kt][i]);
        #pragma unroll
        for (int msk = 1; msk < 16; msk <<= 1) m = fmaxf(m, __shfl_xor(m, msk));
        mx[i] = m;
      }
      if (r == 0) {
        #pragma unroll
        for (int i = 0; i < 4; ++i) sm.a.redm[w][qq * 4 + i] = mx[i];
      }
      __syncthreads();
      #pragma unroll
      for (int i = 0; i < 4; ++i)
        mx[i] = fmaxf(fmaxf(sm.a.redm[0][qq * 4 + i], sm.a.redm[1][qq * 4 + i]),
                      fmaxf(sm.a.redm[2][qq * 4 + i], sm.a.redm[3][qq * 4 + i]));

      float smv[4] = {0.f, 0.f, 0.f, 0.f};
      #pragma unroll
      for (int kt = 0; kt < 16; ++kt)
        #pragma unroll
        for (int i = 0; i < 4; ++i) {
          float e = __expf(sc[kt][i] - mx[i]);
          sc[kt][i] = e;
          smv[i] += e;
        }
      #pragma unroll
      for (int i = 0; i < 4; ++i) {
        float s = smv[i];
        #pragma unroll
        for (int msk = 1; msk < 16; msk <<= 1) s += __shfl_xor(s, msk);
        smv[i] = s;
      }
      if (r == 0) {
        #pragma unroll
        for (int i = 0; i < 4; ++i) sm.a.redsum[w][qq * 4 + i] = smv[i];
      }
      __syncthreads();
      float rinv[4];
      #pragma unroll
      for (int i = 0; i < 4; ++i)
        rinv[i] = 1.0f / (sm.a.redsum[0][qq * 4 + i] + sm.a.redsum[1][qq * 4 + i] +
                          sm.a.redsum[2][qq * 4 + i] + sm.a.redsum[3][qq * 4 + i]);

      float* ap = attnO + ((size_t)bh * S + s0) * S;
      #pragma unroll
      for (int kt = 0; kt < 16; ++kt) {
        int col = w * 256 + kt * 16 + r;
        #pragma unroll
        for (int i = 0; i < 4; ++i) {
          int row = qq * 4 + i;
          ap[(size_t)row * S + col] = sc[kt][i] * rinv[i];
          sm.a.Pl[row * 1024 + (col ^ ((row & 7) << 3))] = f2bf(sc[kt][i]);
        }
      }
      __syncthreads();

      {
        const int d0 = w * 16;
        const ushort* vp = vt + ((size_t)bh * D + d0 + r) * S;
        f32x4 acc[4] = {};
        #pragma unroll
        for (int stp = 0; stp < 32; ++stp) {
          int t0 = stp * 32 + qq * 8;
          bf16x8 pa = *(const bf16x8*)&sm.a.Pl[r * 1024 + (t0 ^ ((r & 7) << 3))];
          bf16x8 vb = *(const bf16x8*)(vp + t0);
          acc[stp & 3] = mfma16(pa, vb, acc[stp & 3]);
        }
        f32x4 tot = acc[0] + acc[1] + acc[2] + acc[3];
        const int b = t >> 9, h = (t >> 6) & 7;
        #pragma unroll
        for (int i = 0; i < 4; ++i)
          concat[((size_t)b * S + s0 + qq * 4 + i) * DM + h * D + d0 + r] =
              f2bf(tot[i] * rinv[i]);
      }
    }
  }
  grid.sync();

  // ---- P3: out-proj GEMM  z[s][m] = sum_f concat[s][f]*WoT[m][f] ---------
  {
    const int w = tid >> 6, l = tid & 63;
    const int r = l & 15, qq = l >> 4;
    const int mh = (w >> 1) * 32, nh = (w & 1) * 32;
    const int srow = tid >> 2, sco = (tid & 3) * 16;
    for (int t = blockIdx.x; t < 1024; t += gridDim.x) {   // 128 x 8 tiles
      const int m0 = (t >> 3) * 64, n0 = (t & 7) * 64;
      f32x4 acc[2][2] = {};
      for (int k0 = 0; k0 < 512; k0 += 64) {
        const ushort* ap = concat + (size_t)(m0 + srow) * 512 + k0 + sco;
        const ushort* bp = WoT + (size_t)(n0 + srow) * 512 + k0 + sco;
        uint4 a0 = *(const uint4*)ap;
        uint4 a1 = *(const uint4*)(ap + 8);
        uint4 b0 = *(const uint4*)bp;
        uint4 b1 = *(const uint4*)(bp + 8);
        __syncthreads();
        *(uint4*)&sm.g.As[srow][sco] = a0;
        *(uint4*)&sm.g.As[srow][sco + 8] = a1;
        *(uint4*)&sm.g.Bs[srow][sco] = b0;
        *(uint4*)&sm.g.Bs[srow][sco + 8] = b1;
        __syncthreads();
        #pragma unroll
        for (int kk = 0; kk < 64; kk += 32) {
          bf16x8 fa0 = *(const bf16x8*)&sm.g.As[mh + r][kk + qq * 8];
          bf16x8 fa1 = *(const bf16x8*)&sm.g.As[mh + 16 + r][kk + qq * 8];
          bf16x8 fb0 = *(const bf16x8*)&sm.g.Bs[nh + r][kk + qq * 8];
          bf16x8 fb1 = *(const bf16x8*)&sm.g.Bs[nh + 16 + r][kk + qq * 8];
          acc[0][0] = mfma16(fa0, fb0, acc[0][0]);
          acc[0][1] = mfma16(fa0, fb1, acc[0][1]);
          acc[1][0] = mfma16(fa1, fb0, acc[1][0]);
          acc[1][1] = mfma16(fa1, fb1, acc[1][1]);
        }
      }
      #pragma unroll
      for (int mi = 0; mi < 2; ++mi)
        #pragma unroll
        for (int nj = 0; nj < 2; ++nj)
          #pragma unroll
          for (int i = 0; i < 4; ++i) {
            int row = m0 + mh + mi * 16 + qq * 4 + i;
            int col = n0 + nh + nj * 16 + r;
            z[(size_t)row * DM + col] = acc[mi][nj][i];
          }
    }
  }
}

// ---------------------------------------------------------------------------
extern "C" void kernel_launch(void* const* d_in, const int* in_sizes, int n_in,
                              void* d_out, int out_size, void* d_ws, size_t ws_size,
                              hipStream_t stream) {
  const float* x  = (const float*)d_in[0];
  const float* Wq = (const float*)d_in[1];
  const float* Wk = (const float*)d_in[2];
  const float* Wv = (const float*)d_in[3];
  const float* Wo = (const float*)d_in[4];

  float* z    = (float*)d_out;                      // [B,S,DM]
  float* attn = z + (size_t)B * S * DM;             // [B,H,S,S]

  ushort* xbf    = (ushort*)d_ws;                   // [8192][512]
  ushort* WT     = xbf + (size_t)8192 * 512;        // [1536][512]
  ushort* WoT    = WT + (size_t)1536 * 512;         // [512][512]
  ushort* qb     = WoT + (size_t)512 * 512;         // [B,H,S,D]
  ushort* kb     = qb + (size_t)B * H * S * D;      // [B,H,S,D]
  ushort* vt     = kb + (size_t)B * H * S * D;      // [B,H,D,S]
  ushort* concat = vt + (size_t)B * H * S * D;      // [8192][512]

  // Co-resident grid size for cooperative launch (cached; host-only query,
  // no stream ops -> graph-capture safe).
  static int grid = 0;
  if (grid == 0) {
    int maxB = 0;
    hipOccupancyMaxActiveBlocksPerMultiprocessor(&maxB, mega_kernel, 256, 0);
    if (maxB < 1) maxB = 1;
    grid = maxB * 256;                              // 256 CUs on MI355X
    if (grid > 1024) grid = 1024;
  }

  void* args[] = {(void*)&x,   (void*)&Wq,  (void*)&Wk,  (void*)&Wv,
                  (void*)&Wo,  (void*)&z,   (void*)&attn, (void*)&xbf,
                  (void*)&WT,  (void*)&WoT, (void*)&qb,  (void*)&kb,
                  (void*)&vt,  (void*)&concat};
  hipLaunchCooperativeKernel((const void*)mega_kernel, dim3(grid), dim3(256),
                             args, 0, stream);
}

// Round 3
// 195.395 us; speedup vs baseline: 3.1295x; 3.1295x over previous
//
#include <hip/hip_runtime.h>

#define B 8
#define S 1024
#define DM 512
#define H 8
#define D 64

typedef __attribute__((ext_vector_type(8))) short bf16x8;
typedef __attribute__((ext_vector_type(4))) float f32x4;

__device__ inline f32x4 mfma16(bf16x8 a, bf16x8 b, f32x4 c) {
  return __builtin_amdgcn_mfma_f32_16x16x32_bf16(a, b, c, 0, 0, 0);
}

__device__ inline ushort f2bf(float f) {
  uint u = __float_as_uint(f);
  u += 0x7fff + ((u >> 16) & 1);   // round-to-nearest-even
  return (ushort)(u >> 16);
}

// async global -> LDS, 16 bytes per lane (dest must be lane-linear!)
#define GLOAD16(gp, lp)                                                  \
  __builtin_amdgcn_global_load_lds(                                      \
      (const __attribute__((address_space(1))) void*)(gp),               \
      (__attribute__((address_space(3))) void*)(lp), 16, 0, 0)

// ---------------------------------------------------------------------------
// Fused prep: cast x f32->bf16 (blocks [0,4096)), transpose-pack Wq/Wk/Wv
// into WT[f][m] (blocks [4096,7168)) and Wo into WoT[m][f] (blocks
// [7168,8192)). W reads are COALESCED (d / m fastest); the 2B scattered
// writes are absorbed by L2 (WT is only 1.5 MiB).
// ---------------------------------------------------------------------------
__global__ __launch_bounds__(256) void prep_kernel(
    const float* __restrict__ x, const float* __restrict__ Wq,
    const float* __restrict__ Wk, const float* __restrict__ Wv,
    const float* __restrict__ Wo, ushort* __restrict__ xbf,
    ushort* __restrict__ WT, ushort* __restrict__ WoT) {
  const int bid = blockIdx.x;
  if (bid < 4096) {                                 // cast x, float4/thread
    int idx = bid * 256 + threadIdx.x;
    float4 v = *(const float4*)(x + (size_t)idx * 4);
    ushort4 o;
    o.x = f2bf(v.x); o.y = f2bf(v.y); o.z = f2bf(v.z); o.w = f2bf(v.w);
    *(ushort4*)(xbf + (size_t)idx * 4) = o;
  } else if (bid < 7168) {                          // Wq/Wk/Wv -> WT[f][m]
    int idx = (bid - 4096) * 256 + threadIdx.x;     // [0, 3*8*512*64)
    int g = idx >> 18;                              // 0=q 1=k 2=v
    int rem = idx & 262143;                         // h*32768 + m*64 + d
    const float* W = (g == 0) ? Wq : (g == 1) ? Wk : Wv;
    float val = W[rem];                             // coalesced read
    int d = rem & 63, m = (rem >> 6) & 511, h = rem >> 15;
    WT[((size_t)(g << 9) + (h << 6) + d) * 512 + m] = f2bf(val);
  } else {                                          // Wo -> WoT[m][f]
    int idx = (bid - 7168) * 256 + threadIdx.x;     // [0, 512*512)
    int m = idx & 511, f = idx >> 9;
    WoT[(size_t)m * 512 + f] = f2bf(Wo[(size_t)f * DM + m]);  // coalesced read
  }
}

// ---------------------------------------------------------------------------
// QKV GEMM: C[s][f] = sum_m xbf[s][m] * WT[f][m]   (M=8192, N=1536, K=512)
// m97 structure: 128x128 tile, 4 waves (each 64x64 = 4x4 16x16 frags),
// linear LDS [128][64] bf16, global_load_lds width 16, 2 barriers/K-step.
// Grid 64x12 = 768 blocks (3/CU). Epilogue scatters to q/k [b,h,s,d] and
// vT [b,h,d,s].
// ---------------------------------------------------------------------------
__global__ __launch_bounds__(256) void qkv_gemm_kernel(
    const ushort* __restrict__ A, const ushort* __restrict__ Bm,
    ushort* __restrict__ qb, ushort* __restrict__ kb, ushort* __restrict__ vt) {
  __shared__ ushort As[128 * 64], Bs[128 * 64];     // 16 KB each, LINEAR
  const int tid = threadIdx.x;
  const int m0 = blockIdx.x * 128, n0 = blockIdx.y * 128;
  const int w = tid >> 6, l = tid & 63;
  const int r = l & 15, q = l >> 4;
  const int wr = (w >> 1) * 64, wc = (w & 1) * 64;  // wave's 64x64 sub-tile

  f32x4 acc[4][4] = {};
  const int o0 = tid * 16;                          // staging byte offset

  for (int k0 = 0; k0 < 512; k0 += 64) {
    __syncthreads();                                // prev-iter LDS reads done
    #pragma unroll
    for (int j = 0; j < 4; ++j) {                   // 4 KB per round
      int o = j * 4096 + o0;                        // tile byte offset
      int row = o >> 7, cb = o & 127;               // 128 B per tile row
      GLOAD16(A + (size_t)(m0 + row) * 512 + k0 + (cb >> 1), &As[o >> 1]);
      GLOAD16(Bm + (size_t)(n0 + row) * 512 + k0 + (cb >> 1), &Bs[o >> 1]);
    }
    __syncthreads();                                // compiler drains vmcnt(0)
    #pragma unroll
    for (int kk = 0; kk < 64; kk += 32) {
      bf16x8 fa[4], fb[4];
      #pragma unroll
      for (int mi = 0; mi < 4; ++mi)
        fa[mi] = *(const bf16x8*)&As[(wr + mi * 16 + r) * 64 + kk + q * 8];
      #pragma unroll
      for (int nj = 0; nj < 4; ++nj)
        fb[nj] = *(const bf16x8*)&Bs[(wc + nj * 16 + r) * 64 + kk + q * 8];
      #pragma unroll
      for (int mi = 0; mi < 4; ++mi)
        #pragma unroll
        for (int nj = 0; nj < 4; ++nj)
          acc[mi][nj] = mfma16(fa[mi], fb[nj], acc[mi][nj]);
    }
  }

  const int g = n0 >> 9;                            // 0=q 1=k 2=v (128|512)
  #pragma unroll
  for (int mi = 0; mi < 4; ++mi)
    #pragma unroll
    for (int nj = 0; nj < 4; ++nj)
      #pragma unroll
      for (int i = 0; i < 4; ++i) {
        int row = m0 + wr + mi * 16 + q * 4 + i;    // global s-row
        int col = n0 + wc + nj * 16 + r;            // global f
        int bb = row >> 10, s = row & 1023;
        int fl = col & 511, h = fl >> 6, d = fl & 63;
        ushort val = f2bf(acc[mi][nj][i]);
        if (g == 0)
          qb[(((size_t)bb * H + h) * S + s) * D + d] = val;
        else if (g == 1)
          kb[(((size_t)bb * H + h) * S + s) * D + d] = val;
        else
          vt[(((size_t)bb * H + h) * D + d) * S + s] = val;
      }
}

// ---------------------------------------------------------------------------
// Attention: block = (b,h, 16 q-rows), 4 waves. Scores stay in registers
// (wave w owns key cols [w*256, w*256+256)); softmax via 16-lane shuffle
// reduce + 512B cross-wave LDS; attn written f32 from regs; P stored ONCE
// as bf16 in XOR-swizzled LDS; PV reads bf16 fragments conflict-free.
// ---------------------------------------------------------------------------
__global__ __launch_bounds__(256, 4) void attn_kernel(
    const ushort* __restrict__ qb, const ushort* __restrict__ kb,
    const ushort* __restrict__ vt, float* __restrict__ attn,
    ushort* __restrict__ concat) {
  __shared__ ushort Pl[16 * 1024];                  // 32 KB, swizzled bf16 P
  __shared__ float redm[4][16], redsum[4][16];      // 512 B
  const int tid = threadIdx.x;
  const int w = tid >> 6, l = tid & 63;
  const int r = l & 15, q = l >> 4;
  const int s0 = blockIdx.x * 16, bh = blockIdx.y;

  // Q fragments (A-operand): lane holds Q[s0+r][q*8..+8] and [32+q*8..+8]
  const ushort* qp = qb + ((size_t)bh * S + s0) * D;
  bf16x8 qa0 = *(const bf16x8*)(qp + r * 64 + q * 8);
  bf16x8 qa1 = *(const bf16x8*)(qp + r * 64 + 32 + q * 8);

  // scores in registers: sc[kt][i] = S[q*4+i][w*256+kt*16+r] * 1/8
  const ushort* kp = kb + (size_t)bh * S * D;
  f32x4 sc[16];
  #pragma unroll
  for (int kt = 0; kt < 16; ++kt) {
    const ushort* kr = kp + (size_t)(w * 256 + kt * 16 + r) * 64 + q * 8;
    bf16x8 kf0 = *(const bf16x8*)kr;
    bf16x8 kf1 = *(const bf16x8*)(kr + 32);
    f32x4 a = {};
    a = mfma16(qa0, kf0, a);
    a = mfma16(qa1, kf1, a);
    sc[kt] = a * 0.125f;
  }

  // row max: lane-local over kt, then across the 16 r-lanes
  float mx[4];
  #pragma unroll
  for (int i = 0; i < 4; ++i) {
    float m = sc[0][i];
    #pragma unroll
    for (int kt = 1; kt < 16; ++kt) m = fmaxf(m, sc[kt][i]);
    #pragma unroll
    for (int msk = 1; msk < 16; msk <<= 1) m = fmaxf(m, __shfl_xor(m, msk));
    mx[i] = m;
  }
  if (r == 0) {
    #pragma unroll
    for (int i = 0; i < 4; ++i) redm[w][q * 4 + i] = mx[i];
  }
  __syncthreads();
  #pragma unroll
  for (int i = 0; i < 4; ++i)
    mx[i] = fmaxf(fmaxf(redm[0][q * 4 + i], redm[1][q * 4 + i]),
                  fmaxf(redm[2][q * 4 + i], redm[3][q * 4 + i]));

  // exp (unnormalized P in regs) + row sums
  float sm[4] = {0.f, 0.f, 0.f, 0.f};
  #pragma unroll
  for (int kt = 0; kt < 16; ++kt)
    #pragma unroll
    for (int i = 0; i < 4; ++i) {
      float e = __expf(sc[kt][i] - mx[i]);
      sc[kt][i] = e;
      sm[i] += e;
    }
  #pragma unroll
  for (int i = 0; i < 4; ++i) {
    float s = sm[i];
    #pragma unroll
    for (int msk = 1; msk < 16; msk <<= 1) s += __shfl_xor(s, msk);
    sm[i] = s;
  }
  if (r == 0) {
    #pragma unroll
    for (int i = 0; i < 4; ++i) redsum[w][q * 4 + i] = sm[i];
  }
  __syncthreads();
  float rinv[4];
  #pragma unroll
  for (int i = 0; i < 4; ++i)
    rinv[i] = 1.0f / (redsum[0][q * 4 + i] + redsum[1][q * 4 + i] +
                      redsum[2][q * 4 + i] + redsum[3][q * 4 + i]);

  // write attn f32 (normalized) + P bf16 (unnormalized) to swizzled LDS
  float* ap = attn + ((size_t)bh * S + s0) * S;
  #pragma unroll
  for (int kt = 0; kt < 16; ++kt) {
    int col = w * 256 + kt * 16 + r;
    #pragma unroll
    for (int i = 0; i < 4; ++i) {
      int row = q * 4 + i;
      ap[(size_t)row * S + col] = sc[kt][i] * rinv[i];
      Pl[row * 1024 + (col ^ ((row & 7) << 3))] = f2bf(sc[kt][i]);
    }
  }
  __syncthreads();

  // PV: wave w owns d-tile [w*16, w*16+16); A = P (LDS), B = V^T (global/L2)
  {
    const int d0 = w * 16;
    const ushort* vp = vt + ((size_t)bh * D + d0 + r) * S;
    f32x4 acc[4] = {};
    #pragma unroll
    for (int stp = 0; stp < 32; ++stp) {
      int t0 = stp * 32 + q * 8;
      bf16x8 pa = *(const bf16x8*)&Pl[r * 1024 + (t0 ^ ((r & 7) << 3))];
      bf16x8 vb = *(const bf16x8*)(vp + t0);
      acc[stp & 3] = mfma16(pa, vb, acc[stp & 3]);
    }
    f32x4 tot = acc[0] + acc[1] + acc[2] + acc[3];
    const int b = bh >> 3, h = bh & 7;
    #pragma unroll
    for (int i = 0; i < 4; ++i)
      concat[((size_t)b * S + s0 + q * 4 + i) * DM + h * D + d0 + r] =
          f2bf(tot[i] * rinv[i]);
  }
}

// ---------------------------------------------------------------------------
// Out-proj GEMM: z[s][m] = sum_f concat[s][f] * WoT[m][f]  (M=8192,N=512,K=512)
// 64x64 tile, 4 waves, reg-staged LDS (+pad): 1024 blocks = 4/CU for TLP.
// ---------------------------------------------------------------------------
__global__ __launch_bounds__(256) void outproj_gemm_kernel(
    const ushort* __restrict__ A, const ushort* __restrict__ Bm,
    float* __restrict__ z) {
  __shared__ ushort As[64][72], Bs[64][72];
  const int tid = threadIdx.x;
  const int m0 = blockIdx.x * 64, n0 = blockIdx.y * 64;
  const int w = tid >> 6, l = tid & 63;
  const int r = l & 15, q = l >> 4;
  const int mh = (w >> 1) * 32, nh = (w & 1) * 32;

  f32x4 acc[2][2] = {};
  const int srow = tid >> 2, sco = (tid & 3) * 16;

  for (int k0 = 0; k0 < 512; k0 += 64) {
    const ushort* ap = A + (size_t)(m0 + srow) * 512 + k0 + sco;
    const ushort* bp = Bm + (size_t)(n0 + srow) * 512 + k0 + sco;
    uint4 a0 = *(const uint4*)ap;
    uint4 a1 = *(const uint4*)(ap + 8);
    uint4 b0 = *(const uint4*)bp;
    uint4 b1 = *(const uint4*)(bp + 8);
    __syncthreads();
    *(uint4*)&As[srow][sco] = a0;
    *(uint4*)&As[srow][sco + 8] = a1;
    *(uint4*)&Bs[srow][sco] = b0;
    *(uint4*)&Bs[srow][sco + 8] = b1;
    __syncthreads();
    #pragma unroll
    for (int kk = 0; kk < 64; kk += 32) {
      bf16x8 fa0 = *(const bf16x8*)&As[mh + r][kk + q * 8];
      bf16x8 fa1 = *(const bf16x8*)&As[mh + 16 + r][kk + q * 8];
      bf16x8 fb0 = *(const bf16x8*)&Bs[nh + r][kk + q * 8];
      bf16x8 fb1 = *(const bf16x8*)&Bs[nh + 16 + r][kk + q * 8];
      acc[0][0] = mfma16(fa0, fb0, acc[0][0]);
      acc[0][1] = mfma16(fa0, fb1, acc[0][1]);
      acc[1][0] = mfma16(fa1, fb0, acc[1][0]);
      acc[1][1] = mfma16(fa1, fb1, acc[1][1]);
    }
  }

  #pragma unroll
  for (int mi = 0; mi < 2; ++mi)
    #pragma unroll
    for (int nj = 0; nj < 2; ++nj)
      #pragma unroll
      for (int i = 0; i < 4; ++i) {
        int row = m0 + mh + mi * 16 + q * 4 + i;
        int col = n0 + nh + nj * 16 + r;
        z[(size_t)row * DM + col] = acc[mi][nj][i];
      }
}

// ---------------------------------------------------------------------------
extern "C" void kernel_launch(void* const* d_in, const int* in_sizes, int n_in,
                              void* d_out, int out_size, void* d_ws, size_t ws_size,
                              hipStream_t stream) {
  const float* x  = (const float*)d_in[0];
  const float* Wq = (const float*)d_in[1];
  const float* Wk = (const float*)d_in[2];
  const float* Wv = (const float*)d_in[3];
  const float* Wo = (const float*)d_in[4];

  float* z    = (float*)d_out;                      // [B,S,DM]
  float* attn = z + (size_t)B * S * DM;             // [B,H,S,S]

  ushort* xbf    = (ushort*)d_ws;                   // [8192][512]
  ushort* WT     = xbf + (size_t)8192 * 512;        // [1536][512]
  ushort* WoT    = WT + (size_t)1536 * 512;         // [512][512]
  ushort* qb     = WoT + (size_t)512 * 512;         // [B,H,S,D]
  ushort* kb     = qb + (size_t)B * H * S * D;      // [B,H,S,D]
  ushort* vt     = kb + (size_t)B * H * S * D;      // [B,H,D,S]
  ushort* concat = vt + (size_t)B * H * S * D;      // [8192][512]

  prep_kernel<<<8192, 256, 0, stream>>>(x, Wq, Wk, Wv, Wo, xbf, WT, WoT);
  qkv_gemm_kernel<<<dim3(8192 / 128, 1536 / 128), 256, 0, stream>>>(
      xbf, WT, qb, kb, vt);
  attn_kernel<<<dim3(S / 16, B * H), 256, 0, stream>>>(
      qb, kb, vt, attn, concat);
  outproj_gemm_kernel<<<dim3(8192 / 64, 512 / 64), 256, 0, stream>>>(
      concat, WoT, z);
}